// Round 10
// baseline (198.016 us; speedup 1.0000x reference)
//
#include <hip/hip_runtime.h>
#include <hip/hip_fp16.h>

#define B_   32
#define C_   16
#define H_   256
#define W_   256
#define HW_  65536      // H_*W_
#define HID_ 128
#define T_   4          // rows per block
#define NBLK_ (B_*H_/T_)   // 2048 blocks, 64 per image

typedef __attribute__((ext_vector_type(8))) _Float16 f16x8;
typedef __attribute__((ext_vector_type(2))) _Float16 f16x2;
typedef __attribute__((ext_vector_type(4))) float    f32x4;

__device__ __forceinline__ int h2i(f16x2 h) { return __builtin_bit_cast(int, h); }
__device__ __forceinline__ f16x2 i2h(int i) { return __builtin_bit_cast(f16x2, i); }

__device__ __forceinline__ f16x2 pk(float a, float b) {
    f16x2 r; r.x = (_Float16)a; r.y = (_Float16)b; return r;
}

// ---------------- prep: fold w1 -> f16 pair coefs; pack w2 -> f16 A-frags ----
__global__ __launch_bounds__(128) void nca_prep(
    const float* __restrict__ w1, const float* __restrict__ b1,
    const float* __restrict__ w2,
    int4* __restrict__ coefH, short* __restrict__ w2h)
{
    __shared__ float4 tmp[128];
    int o = threadIdx.x;   // 0..127
    float A = 0.f, Bc = 0.f, Cc = 0.f;
    #pragma unroll
    for (int k = 0;  k < 16; ++k) A  += w1[o*48 + k];
    #pragma unroll
    for (int k = 16; k < 32; ++k) Bc += w1[o*48 + k];
    #pragma unroll
    for (int k = 32; k < 48; ++k) Cc += w1[o*48 + k];
    tmp[o] = make_float4(A, Bc, Cc, b1[o]);
    __syncthreads();
    if (o < 64) {
        float4 e = tmp[2*o], f = tmp[2*o+1];
        coefH[o] = make_int4(h2i(pk(e.x, f.x)), h2i(pk(e.y, f.y)),
                             h2i(pk(e.z, f.z)), h2i(pk(e.w, f.w)));
    }
    // layer-2 A-frags, f16, fragment-ordered: entry e=(kb,l) -> 8 halves
    for (int e = threadIdx.x; e < 256; e += 128) {
        const int kb = e >> 6, l = e & 63;
        const int qq = l & 15, gg = l >> 4;
        const float* wp = w2 + qq*HID_ + kb*32 + gg*8;
        f16x8 a;
        #pragma unroll
        for (int j = 0; j < 8; ++j) a[j] = (_Float16)wp[j];
        *(f16x8*)(w2h + e*8) = a;
    }
}

// ---------------- fused: wave-independent tiles, NO __syncthreads ------------
// Wave = 64 cols × T_ rows. Rolling 3-row sum window in wave-private LDS
// swave[3][66] (2 halo cols via 32-lane side-channel + shfl reduce).
// Layer 1: packed v_pk_fma_f16; Layer 2: mfma 16x16x32_f16 (validated path).
// No register prefetch: 32 waves/CU of TLP hides HBM/L2 latency instead.
__global__ __launch_bounds__(256, 6) void nca_fused(
    const float* __restrict__ x, const int* __restrict__ mask,
    const int4* __restrict__ coefH, const short* __restrict__ w2h,
    const float* __restrict__ b2,
    float* __restrict__ out, unsigned char* __restrict__ alpha)
{
    __shared__ short hlds[4*2048];     // 16 KB: per-wave 4KB h-tile
    __shared__ float swave[4][3][66];  // 3.1 KB: per-wave rolling sum window

    const int tid  = threadIdx.x;
    const int lane = tid & 63;
    const int widx = tid >> 6;
    const int col  = tid;              // this lane's column (c0 + lane)
    const int c0   = widx << 6;
    const int q = lane & 15;           // MFMA col lane
    const int g = lane >> 4;           // MFMA k-group

    const int blk = blockIdx.x;
    const int b   = blk >> 6;          // 64 blocks per image
    const int r0  = (blk & 63) * T_;

    const float* xb = x    + (size_t)b * C_ * HW_;
    const int*   mb = mask + (size_t)b * HW_;
    float*       ob = (float*)out + (size_t)b * C_ * HW_;
    unsigned char* ab = alpha + (size_t)b * HW_;

    float (*sw)[66] = swave[widx];

    f32x4 bias;
    #pragma unroll
    for (int r = 0; r < 4; ++r) bias[r] = b2[g*4 + r];

    const int wswz = (lane ^ (lane >> 2)) & 3;   // h-tile write swizzle
    const int rsw  = (q ^ (q >> 2)) & 3;         // h-tile read swizzle
    short* hw = hlds + widx*2048;                // 4KB per wave

    // halo side-channel geometry (lanes 0..31): 2 halo cols × 16 channels
    const int hc   = (lane < 16) ? (c0 - 1) : (c0 + 64);
    const bool hok = (lane < 32) && (hc >= 0) && (hc < W_);

    // ---- prologue: sums for rows r0-1 (slot 0) and r0 (slot 1) -------------
    {
        float s0 = 0.f, s1 = 0.f, h0 = 0.f, h1 = 0.f;
        if (r0 > 0) {
            #pragma unroll
            for (int c = 0; c < C_; ++c) s0 += xb[c*HW_ + (r0-1)*W_ + col];
            if (hok) h0 = xb[(lane & 15)*HW_ + (r0-1)*W_ + hc];
        }
        #pragma unroll
        for (int c = 0; c < C_; ++c) s1 += xb[c*HW_ + r0*W_ + col];
        if (hok) h1 = xb[(lane & 15)*HW_ + r0*W_ + hc];
        #pragma unroll
        for (int o = 1; o < 16; o <<= 1) {
            h0 += __shfl_xor(h0, o);
            h1 += __shfl_xor(h1, o);
        }
        sw[0][1+lane] = s0;
        sw[1][1+lane] = s1;
        if (lane == 0)  { sw[0][0]  = h0; sw[1][0]  = h1; }
        if (lane == 16) { sw[0][65] = h0; sw[1][65] = h1; }
    }
    __builtin_amdgcn_wave_barrier();

    for (int r = 0; r < T_; ++r) {
        const int row  = r0 + r;
        const int nr   = row + 1;
        const int slot = (r + 2) % 3;

        // ---- sum of row+1 into rolling slot (0 below image bottom) ----------
        {
            float s = 0.f, hv = 0.f;
            if (nr < H_) {
                #pragma unroll
                for (int c = 0; c < C_; ++c) s += xb[c*HW_ + nr*W_ + col];
                if (hok) hv = xb[(lane & 15)*HW_ + nr*W_ + hc];
            }
            #pragma unroll
            for (int o = 1; o < 16; o <<= 1) hv += __shfl_xor(hv, o);
            sw[slot][1+lane] = s;
            if (lane == 0)  sw[slot][0]  = hv;
            if (lane == 16) sw[slot][65] = hv;
        }
        __builtin_amdgcn_wave_barrier();

        // ---- sobel from rolling window (halo cols already zero-padded) ------
        const float* sAp = sw[(r    ) % 3];
        const float* sBp = sw[(r + 1) % 3];
        const float* sCp = sw[(r + 2) % 3];
        float n00 = sAp[lane], n01 = sAp[lane+1], n02 = sAp[lane+2];
        float n10 = sBp[lane],                    n12 = sBp[lane+2];
        float n20 = sCp[lane], n21 = sCp[lane+1], n22 = sCp[lane+2];
        float px = (n02 - n00) + 2.f*(n12 - n10) + (n22 - n20);
        float py = (n20 - n00) + 2.f*(n21 - n01) + (n22 - n02);
        float sc = sBp[lane+1];

        const f16x2 px2 = pk(px, px);
        const f16x2 py2 = pk(py, py);
        const f16x2 sc2 = pk(sc, sc);
        const f16x2 z2  = pk(0.f, 0.f);

        // mask for this wave's 64-px strip
        const int pstrip = row*W_ + c0;
        float mv[4];
        #pragma unroll
        for (int t = 0; t < 4; ++t) mv[t] = (float)mb[pstrip + t*16 + q];

        f32x4 acc[4];
        #pragma unroll
        for (int t = 0; t < 4; ++t) acc[t] = bias;

        #pragma unroll
        for (int kb = 0; kb < 4; ++kb) {
            // layer 1: 8 hidden per chunk; coefH uniform-indexed -> s_load
            #pragma unroll
            for (int c = 0; c < 4; ++c) {
                int hd[4];
                #pragma unroll
                for (int u = 0; u < 4; ++u) {
                    const int4 cw = coefH[kb*16 + c*4 + u];
                    f16x2 h2 = __builtin_elementwise_fma(i2h(cw.x), px2,
                               __builtin_elementwise_fma(i2h(cw.y), py2,
                               __builtin_elementwise_fma(i2h(cw.z), sc2,
                                                         i2h(cw.w))));
                    h2 = __builtin_elementwise_max(h2, z2);
                    hd[u] = h2i(h2);
                }
                *(int4*)(hw + lane*32 + ((c ^ wswz) << 3)) =
                    make_int4(hd[0], hd[1], hd[2], hd[3]);
            }
            __builtin_amdgcn_wave_barrier();
            // layer-2 A-frag: 16B from prep-packed table (L2-hot, transient)
            const f16x8 af = *(const f16x8*)(w2h + (kb*64 + lane)*8);
            #pragma unroll
            for (int t = 0; t < 4; ++t) {
                const int pp = t*16 + q;
                f16x8 hbf = *(const f16x8*)(hw + pp*32 + (((g ^ rsw) & 3) << 3));
                acc[t] = __builtin_amdgcn_mfma_f32_16x16x32_f16(
                             af, hbf, acc[t], 0, 0, 0);
            }
            __builtin_amdgcn_wave_barrier();
        }

        // ---- epilogue: direct stores, lane holds dx[ch=g*4+e][px=t*16+q] ----
        #pragma unroll
        for (int t = 0; t < 4; ++t) {
            const int pp = pstrip + t*16 + q;
            float xn3 = 0.f;
            #pragma unroll
            for (int e = 0; e < 4; ++e) {
                const int chn = g*4 + e;
                float xv = xb[chn*HW_ + pp];     // recently-summed -> cache hit
                float xn = fmaf(acc[t][e], mv[t], xv);
                ob[chn*HW_ + pp] = xn;
                if (chn == 3) xn3 = xn;
            }
            if (g == 0) ab[pp] = (xn3 > 0.1f) ? (unsigned char)1
                                              : (unsigned char)0;
        }
        __builtin_amdgcn_wave_barrier();   // swave slot reuse next iteration
    }
}

// ---------------- k3: kill pixels with no alive neighbor ---------------------
__global__ __launch_bounds__(256) void nca_alive(
    const unsigned char* __restrict__ alpha, float* __restrict__ out)
{
    int t = blockIdx.x * blockDim.x + threadIdx.x;
    if (t >= B_*HW_) return;
    int b = t >> 16;
    int p = t & (HW_-1);
    int i = p >> 8;
    int j = p & (W_-1);
    const unsigned char* ab = alpha + (size_t)b * HW_;

    bool im = i > 0, ip = i < H_-1, jm = j > 0, jp = j < W_-1;
    int acc = ab[p];
    acc += jm ? ab[p-1] : 0;
    acc += jp ? ab[p+1] : 0;
    if (im) {
        acc += ab[p-W_];
        acc += jm ? ab[p-W_-1] : 0;
        acc += jp ? ab[p-W_+1] : 0;
    }
    if (ip) {
        acc += ab[p+W_];
        acc += jm ? ab[p+W_-1] : 0;
        acc += jp ? ab[p+W_+1] : 0;
    }
    if (acc == 0) {
        size_t base = (size_t)b * C_ * HW_ + p;
        #pragma unroll
        for (int c = 0; c < C_; ++c) out[base + (size_t)c * HW_] = 0.f;
    }
}

extern "C" void kernel_launch(void* const* d_in, const int* in_sizes, int n_in,
                              void* d_out, int out_size, void* d_ws, size_t ws_size,
                              hipStream_t stream)
{
    const float* x    = (const float*)d_in[0];
    const int*   mask = (const int*)d_in[1];
    const float* w1   = (const float*)d_in[2];
    const float* b1   = (const float*)d_in[3];
    const float* w2   = (const float*)d_in[4];
    const float* b2   = (const float*)d_in[5];
    float* out = (float*)d_out;

    // ws layout: alpha (B*HW bytes) | coefH (64×16B) | w2h (256×16B)
    char* ws = (char*)d_ws;
    unsigned char* alpha = (unsigned char*)ws;
    int4*          coefH = (int4*)(ws + (size_t)B_*HW_);
    short*         w2h   = (short*)(ws + (size_t)B_*HW_ + 1024);

    nca_prep<<<1, 128, 0, stream>>>(w1, b1, w2, coefH, w2h);

    nca_fused<<<NBLK_, 256, 0, stream>>>(x, mask, coefH, w2h, b2, out, alpha);

    int n = B_*HW_;
    nca_alive<<<(n + 255)/256, 256, 0, stream>>>(alpha, out);
}

// Round 11
// 168.587 us; speedup vs baseline: 1.1746x; 1.1746x over previous
//
#include <hip/hip_runtime.h>
#include <hip/hip_fp16.h>

#define B_   32
#define C_   16
#define H_   256
#define W_   256
#define HW_  65536      // H_*W_
#define HID_ 128
#define T_   4          // rows per block (= waves per block; 1 row per wave)
#define NBLK_ (B_*H_/T_)   // 2048 blocks, 64 per image

typedef __attribute__((ext_vector_type(8))) _Float16 f16x8;
typedef __attribute__((ext_vector_type(2))) _Float16 f16x2;
typedef __attribute__((ext_vector_type(4))) float    f32x4;

__device__ __forceinline__ int h2i(f16x2 h) { return __builtin_bit_cast(int, h); }
__device__ __forceinline__ f16x2 i2h(int i) { return __builtin_bit_cast(f16x2, i); }

__device__ __forceinline__ f16x2 pk(float a, float b) {
    f16x2 r; r.x = (_Float16)a; r.y = (_Float16)b; return r;
}

// ---------------- prep: fold w1 -> f16 pair coefs; pack w2 -> f16 A-frags ----
__global__ __launch_bounds__(128) void nca_prep(
    const float* __restrict__ w1, const float* __restrict__ b1,
    const float* __restrict__ w2,
    int4* __restrict__ coefH, short* __restrict__ w2h)
{
    __shared__ float4 tmp[128];
    int o = threadIdx.x;   // 0..127
    float A = 0.f, Bc = 0.f, Cc = 0.f;
    #pragma unroll
    for (int k = 0;  k < 16; ++k) A  += w1[o*48 + k];
    #pragma unroll
    for (int k = 16; k < 32; ++k) Bc += w1[o*48 + k];
    #pragma unroll
    for (int k = 32; k < 48; ++k) Cc += w1[o*48 + k];
    tmp[o] = make_float4(A, Bc, Cc, b1[o]);
    __syncthreads();
    if (o < 64) {
        float4 e = tmp[2*o], f = tmp[2*o+1];
        coefH[o] = make_int4(h2i(pk(e.x, f.x)), h2i(pk(e.y, f.y)),
                             h2i(pk(e.z, f.z)), h2i(pk(e.w, f.w)));
    }
    // layer-2 A-frags, f16, fragment-ordered: entry e=(kb,l) -> 8 halves
    for (int e = threadIdx.x; e < 256; e += 128) {
        const int kb = e >> 6, l = e & 63;
        const int qq = l & 15, gg = l >> 4;
        const float* wp = w2 + qq*HID_ + kb*32 + gg*8;
        f16x8 a;
        #pragma unroll
        for (int j = 0; j < 8; ++j) a[j] = (_Float16)wp[j];
        *(f16x8*)(w2h + e*8) = a;
    }
}

// ---------------- fused: 2-phase, ONE __syncthreads per block ----------------
// Phase 1: 256 threads (col=tid) sum T_+2 full rows into srow (coalesced 1KB
// per load instruction, 6 independent chains of ILP).   -- one barrier --
// Phase 2: wave w owns row r0+w entirely (4 strips of 64px); sobel reads the
// now-read-only srow, h-tile is wave-private -> NO further block sync; waves
// drift freely, hiding each other's latency.
// Block swizzle: XCD-chunked bijective (2048%8==0) so vertically adjacent
// bands share an XCD L2 and halo rows are fetched once.
__global__ __launch_bounds__(256, 6) void nca_fused(
    const float* __restrict__ x, const int* __restrict__ mask,
    const int4* __restrict__ coefH, const short* __restrict__ w2h,
    const float* __restrict__ b2,
    float* __restrict__ out, unsigned char* __restrict__ alpha)
{
    __shared__ float srow[T_+2][W_];   // 6 KB row sums (rows r0-1 .. r0+T_)
    __shared__ short hlds[4*2048];     // 16 KB: per-wave 4KB h-tile

    const int tid  = threadIdx.x;
    const int lane = tid & 63;
    const int widx = tid >> 6;
    const int col  = tid;              // phase-1 column
    const int q = lane & 15;           // MFMA col lane
    const int g = lane >> 4;           // MFMA k-group

    // XCD-chunked swizzle: consecutive blk (adjacent bands) -> same XCD
    const int bid = blockIdx.x;
    const int blk = (bid & 7) * (NBLK_ >> 3) + (bid >> 3);
    const int b   = blk >> 6;          // 64 blocks per image
    const int r0  = (blk & 63) * T_;

    const float* xb = x    + (size_t)b * C_ * HW_;
    const int*   mb = mask + (size_t)b * HW_;
    float*       ob = (float*)out + (size_t)b * C_ * HW_;
    unsigned char* ab = alpha + (size_t)b * HW_;

    // ---- phase 1: channel-sums for rows r0-1 .. r0+T_ ----------------------
    #pragma unroll 2
    for (int rr = 0; rr < T_+2; ++rr) {
        const int gr = r0 - 1 + rr;
        float s = 0.f;
        if (gr >= 0 && gr < H_) {
            #pragma unroll
            for (int c = 0; c < C_; ++c) s += xb[c*HW_ + gr*W_ + col];
        }
        srow[rr][col] = s;
    }
    __syncthreads();   // the ONLY block-wide barrier

    // ---- phase 2: this wave owns row r0+widx --------------------------------
    const int row = r0 + widx;
    f32x4 bias;
    #pragma unroll
    for (int r = 0; r < 4; ++r) bias[r] = b2[g*4 + r];

    const int wswz = (lane ^ (lane >> 2)) & 3;   // h-tile write swizzle
    const int rsw  = (q ^ (q >> 2)) & 3;         // h-tile read swizzle
    short* hw = hlds + widx*2048;                // 4KB per wave
    const float* sA = srow[widx];
    const float* sB = srow[widx+1];
    const float* sC = srow[widx+2];

    for (int strip = 0; strip < 4; ++strip) {
        const int c0s  = strip << 6;
        const int col2 = c0s + lane;

        // ---- sobel from block-shared sums (read-only now) ----
        const bool jm = col2 > 0, jp = col2 < W_-1;
        float n00 = jm ? sA[col2-1] : 0.f, n01 = sA[col2], n02 = jp ? sA[col2+1] : 0.f;
        float n10 = jm ? sB[col2-1] : 0.f,                 n12 = jp ? sB[col2+1] : 0.f;
        float n20 = jm ? sC[col2-1] : 0.f, n21 = sC[col2], n22 = jp ? sC[col2+1] : 0.f;
        float px = (n02 - n00) + 2.f*(n12 - n10) + (n22 - n20);
        float py = (n20 - n00) + 2.f*(n21 - n01) + (n22 - n02);
        float sc = sB[col2];

        const f16x2 px2 = pk(px, px);
        const f16x2 py2 = pk(py, py);
        const f16x2 sc2 = pk(sc, sc);
        const f16x2 z2  = pk(0.f, 0.f);

        // mask for this strip
        const int pstrip = row*W_ + c0s;
        float mv[4];
        #pragma unroll
        for (int t = 0; t < 4; ++t) mv[t] = (float)mb[pstrip + t*16 + q];

        f32x4 acc[4];
        #pragma unroll
        for (int t = 0; t < 4; ++t) acc[t] = bias;

        #pragma unroll
        for (int kb = 0; kb < 4; ++kb) {
            // layer 1: 8 hidden per chunk; coefH uniform-indexed -> s_load
            #pragma unroll
            for (int c = 0; c < 4; ++c) {
                int hd[4];
                #pragma unroll
                for (int u = 0; u < 4; ++u) {
                    const int4 cw = coefH[kb*16 + c*4 + u];
                    f16x2 h2 = __builtin_elementwise_fma(i2h(cw.x), px2,
                               __builtin_elementwise_fma(i2h(cw.y), py2,
                               __builtin_elementwise_fma(i2h(cw.z), sc2,
                                                         i2h(cw.w))));
                    h2 = __builtin_elementwise_max(h2, z2);
                    hd[u] = h2i(h2);
                }
                *(int4*)(hw + lane*32 + ((c ^ wswz) << 3)) =
                    make_int4(hd[0], hd[1], hd[2], hd[3]);
            }
            __builtin_amdgcn_wave_barrier();
            // layer-2 A-frag: 16B from prep-packed table (L2-hot)
            const f16x8 af = *(const f16x8*)(w2h + (kb*64 + lane)*8);
            #pragma unroll
            for (int t = 0; t < 4; ++t) {
                const int pp = t*16 + q;
                f16x8 hbf = *(const f16x8*)(hw + pp*32 + (((g ^ rsw) & 3) << 3));
                acc[t] = __builtin_amdgcn_mfma_f32_16x16x32_f16(
                             af, hbf, acc[t], 0, 0, 0);
            }
            __builtin_amdgcn_wave_barrier();
        }

        // ---- epilogue: direct stores, lane holds dx[ch=g*4+e][px=t*16+q] ----
        #pragma unroll
        for (int t = 0; t < 4; ++t) {
            const int pp = pstrip + t*16 + q;
            float xn3 = 0.f;
            #pragma unroll
            for (int e = 0; e < 4; ++e) {
                const int chn = g*4 + e;
                float xv = xb[chn*HW_ + pp];     // summed in phase 1 -> L2 hit
                float xn = fmaf(acc[t][e], mv[t], xv);
                ob[chn*HW_ + pp] = xn;
                if (chn == 3) xn3 = xn;
            }
            if (g == 0) ab[pp] = (xn3 > 0.1f) ? (unsigned char)1
                                              : (unsigned char)0;
        }
        __builtin_amdgcn_wave_barrier();   // h-tile reuse next strip
    }
}

// ---------------- k3: kill pixels with no alive neighbor ---------------------
__global__ __launch_bounds__(256) void nca_alive(
    const unsigned char* __restrict__ alpha, float* __restrict__ out)
{
    int t = blockIdx.x * blockDim.x + threadIdx.x;
    if (t >= B_*HW_) return;
    int b = t >> 16;
    int p = t & (HW_-1);
    int i = p >> 8;
    int j = p & (W_-1);
    const unsigned char* ab = alpha + (size_t)b * HW_;

    bool im = i > 0, ip = i < H_-1, jm = j > 0, jp = j < W_-1;
    int acc = ab[p];
    acc += jm ? ab[p-1] : 0;
    acc += jp ? ab[p+1] : 0;
    if (im) {
        acc += ab[p-W_];
        acc += jm ? ab[p-W_-1] : 0;
        acc += jp ? ab[p-W_+1] : 0;
    }
    if (ip) {
        acc += ab[p+W_];
        acc += jm ? ab[p+W_-1] : 0;
        acc += jp ? ab[p+W_+1] : 0;
    }
    if (acc == 0) {
        size_t base = (size_t)b * C_ * HW_ + p;
        #pragma unroll
        for (int c = 0; c < C_; ++c) out[base + (size_t)c * HW_] = 0.f;
    }
}

extern "C" void kernel_launch(void* const* d_in, const int* in_sizes, int n_in,
                              void* d_out, int out_size, void* d_ws, size_t ws_size,
                              hipStream_t stream)
{
    const float* x    = (const float*)d_in[0];
    const int*   mask = (const int*)d_in[1];
    const float* w1   = (const float*)d_in[2];
    const float* b1   = (const float*)d_in[3];
    const float* w2   = (const float*)d_in[4];
    const float* b2   = (const float*)d_in[5];
    float* out = (float*)d_out;

    // ws layout: alpha (B*HW bytes) | coefH (64×16B) | w2h (256×16B)
    char* ws = (char*)d_ws;
    unsigned char* alpha = (unsigned char*)ws;
    int4*          coefH = (int4*)(ws + (size_t)B_*HW_);
    short*         w2h   = (short*)(ws + (size_t)B_*HW_ + 1024);

    nca_prep<<<1, 128, 0, stream>>>(w1, b1, w2, coefH, w2h);

    nca_fused<<<NBLK_, 256, 0, stream>>>(x, mask, coefH, w2h, b2, out, alpha);

    int n = B_*HW_;
    nca_alive<<<(n + 255)/256, 256, 0, stream>>>(alpha, out);
}

// Round 12
// 104.702 us; speedup vs baseline: 1.8912x; 1.6102x over previous
//
#include <hip/hip_runtime.h>
#include <hip/hip_fp16.h>

#define B_   32
#define C_   16
#define H_   256
#define W_   256
#define HW_  65536      // H_*W_
#define HID_ 128

typedef __attribute__((ext_vector_type(8))) _Float16 f16x8;
typedef __attribute__((ext_vector_type(2))) _Float16 f16x2;
typedef __attribute__((ext_vector_type(4))) float    f32x4;

__device__ __forceinline__ int h2i(f16x2 h) { return __builtin_bit_cast(int, h); }
__device__ __forceinline__ f16x2 i2h(int i) { return __builtin_bit_cast(f16x2, i); }

__device__ __forceinline__ f16x2 pk(float a, float b) {
    f16x2 r; r.x = (_Float16)a; r.y = (_Float16)b; return r;
}

// ---------------- prep: fold w1 -> f16 pair coefs; pack w2 -> f16 A-frags ----
__global__ __launch_bounds__(128) void nca_prep(
    const float* __restrict__ w1, const float* __restrict__ b1,
    const float* __restrict__ w2,
    int4* __restrict__ coefH, short* __restrict__ w2h)
{
    __shared__ float4 tmp[128];
    int o = threadIdx.x;   // 0..127
    float A = 0.f, Bc = 0.f, Cc = 0.f;
    #pragma unroll
    for (int k = 0;  k < 16; ++k) A  += w1[o*48 + k];
    #pragma unroll
    for (int k = 16; k < 32; ++k) Bc += w1[o*48 + k];
    #pragma unroll
    for (int k = 32; k < 48; ++k) Cc += w1[o*48 + k];
    tmp[o] = make_float4(A, Bc, Cc, b1[o]);
    __syncthreads();
    if (o < 64) {
        float4 e = tmp[2*o], f = tmp[2*o+1];
        coefH[o] = make_int4(h2i(pk(e.x, f.x)), h2i(pk(e.y, f.y)),
                             h2i(pk(e.z, f.z)), h2i(pk(e.w, f.w)));
    }
    // layer-2 A-frags, f16, fragment-ordered: entry e=(kb,l) -> 8 halves
    for (int e = threadIdx.x; e < 256; e += 128) {
        const int kb = e >> 6, l = e & 63;
        const int qq = l & 15, gg = l >> 4;
        const float* wp = w2 + qq*HID_ + kb*32 + gg*8;
        f16x8 a;
        #pragma unroll
        for (int j = 0; j < 8; ++j) a[j] = (_Float16)wp[j];
        *(f16x8*)(w2h + e*8) = a;
    }
}

// ---------------- k1: xs[b,p] = sum over 16 channels, float4 vectorized ------
// Simple streaming kernel: saturates HBM/L3, no sync, no reuse needed.
__global__ __launch_bounds__(256) void nca_sum(
    const float* __restrict__ x, float* __restrict__ xs)
{
    int t = blockIdx.x * blockDim.x + threadIdx.x;   // float4 index
    if (t >= B_*HW_/4) return;
    int b  = t >> 14;
    int p4 = (t << 2) & (HW_-1);
    const float* xp = x + (size_t)b * C_ * HW_ + p4;
    float4 s = make_float4(0.f, 0.f, 0.f, 0.f);
    #pragma unroll
    for (int c = 0; c < C_; ++c) {
        float4 v = *(const float4*)(xp + (size_t)c * HW_);
        s.x += v.x; s.y += v.y; s.z += v.z; s.w += v.w;
    }
    ((float4*)xs)[t] = s;
}

// ---------------- k2: sobel + f16 MLP (layer2 MFMA) + update + alpha ---------
// One wave per image row (8192 waves total, no loops over rows, no block
// sync). Per 64-px strip: prefetch x/mask -> sobel from xs -> f16 packed
// layer-1 -> wave-private LDS h-tile -> f16 MFMA layer-2 -> direct stores.
// A-frags/bias hoisted once per wave (row-invariant).
__global__ __launch_bounds__(256, 4) void nca_mlp(
    const float* __restrict__ x, const int* __restrict__ mask,
    const float* __restrict__ xs, const int4* __restrict__ coefH,
    const short* __restrict__ w2h, const float* __restrict__ b2,
    float* __restrict__ out, unsigned char* __restrict__ alpha)
{
    __shared__ short hlds[4*2048];     // 16 KB: per-wave 4KB h-tile

    const int tid  = threadIdx.x;
    const int lane = tid & 63;
    const int widx = tid >> 6;
    const int q = lane & 15;           // MFMA col lane
    const int g = lane >> 4;           // MFMA k-group

    const int w = (blockIdx.x * 256 + tid) >> 6;   // wave id = row id
    const int b = w >> 8;                          // image
    const int i = w & (H_-1);                      // row

    const float* xb  = x    + (size_t)b * C_ * HW_;
    const int*   mb  = mask + (size_t)b * HW_;
    const float* xsb = xs   + (size_t)b * HW_;
    float*       ob  = (float*)out + (size_t)b * C_ * HW_;
    unsigned char* ab = alpha + (size_t)b * HW_;

    // hoist row-invariant fragments
    f16x8 af2[4];
    #pragma unroll
    for (int kb = 0; kb < 4; ++kb)
        af2[kb] = *(const f16x8*)(w2h + (kb*64 + lane)*8);
    f32x4 bias;
    #pragma unroll
    for (int r = 0; r < 4; ++r) bias[r] = b2[g*4 + r];

    const int wswz = (lane ^ (lane >> 2)) & 3;   // h-tile write swizzle
    const int rsw  = (q ^ (q >> 2)) & 3;         // h-tile read swizzle
    short* hw = hlds + widx*2048;
    const bool im = i > 0, ip = i < H_-1;

    for (int strip = 0; strip < 4; ++strip) {
        const int c0s = strip << 6;
        const int jj  = c0s + lane;
        const int p   = i*W_ + jj;
        const int pst = i*W_ + c0s;

        // ---- prefetch epilogue inputs (independent -> issue early) ----------
        float xv[4][4];
        float mv[4];
        #pragma unroll
        for (int t = 0; t < 4; ++t) {
            mv[t] = (float)mb[pst + t*16 + q];
            #pragma unroll
            for (int e = 0; e < 4; ++e)
                xv[t][e] = xb[(g*4 + e)*HW_ + pst + t*16 + q];
        }

        // ---- sobel on channel-sums ----
        const bool jm = jj > 0, jp = jj < W_-1;
        float n11 = xsb[p];
        float n10 = jm ? xsb[p-1]  : 0.f;
        float n12 = jp ? xsb[p+1]  : 0.f;
        float n01 = im ? xsb[p-W_] : 0.f;
        float n00 = (im && jm) ? xsb[p-W_-1] : 0.f;
        float n02 = (im && jp) ? xsb[p-W_+1] : 0.f;
        float n21 = ip ? xsb[p+W_] : 0.f;
        float n20 = (ip && jm) ? xsb[p+W_-1] : 0.f;
        float n22 = (ip && jp) ? xsb[p+W_+1] : 0.f;
        float px = (n02 - n00) + 2.f*(n12 - n10) + (n22 - n20);
        float py = (n20 - n00) + 2.f*(n21 - n01) + (n22 - n02);
        float sc = n11;

        const f16x2 px2 = pk(px, px);
        const f16x2 py2 = pk(py, py);
        const f16x2 sc2 = pk(sc, sc);
        const f16x2 z2  = pk(0.f, 0.f);

        f32x4 acc[4];
        #pragma unroll
        for (int t = 0; t < 4; ++t) acc[t] = bias;

        #pragma unroll
        for (int kb = 0; kb < 4; ++kb) {
            // layer 1: 8 hidden per chunk; coefH uniform-indexed -> s_load
            #pragma unroll
            for (int c = 0; c < 4; ++c) {
                int hd[4];
                #pragma unroll
                for (int u = 0; u < 4; ++u) {
                    const int4 cw = coefH[kb*16 + c*4 + u];
                    f16x2 h2 = __builtin_elementwise_fma(i2h(cw.x), px2,
                               __builtin_elementwise_fma(i2h(cw.y), py2,
                               __builtin_elementwise_fma(i2h(cw.z), sc2,
                                                         i2h(cw.w))));
                    h2 = __builtin_elementwise_max(h2, z2);
                    hd[u] = h2i(h2);
                }
                *(int4*)(hw + lane*32 + ((c ^ wswz) << 3)) =
                    make_int4(hd[0], hd[1], hd[2], hd[3]);
            }
            __builtin_amdgcn_wave_barrier();
            // layer 2: 4 groups of 16 px (validated fragment mapping)
            #pragma unroll
            for (int t = 0; t < 4; ++t) {
                const int pp = t*16 + q;
                f16x8 hbf = *(const f16x8*)(hw + pp*32 + (((g ^ rsw) & 3) << 3));
                acc[t] = __builtin_amdgcn_mfma_f32_16x16x32_f16(
                             af2[kb], hbf, acc[t], 0, 0, 0);
            }
            __builtin_amdgcn_wave_barrier();
        }

        // ---- epilogue: direct stores, lane holds dx[ch=g*4+e][px=t*16+q] ----
        #pragma unroll
        for (int t = 0; t < 4; ++t) {
            const int pp = pst + t*16 + q;
            float xn3 = 0.f;
            #pragma unroll
            for (int e = 0; e < 4; ++e) {
                const int chn = g*4 + e;
                float xn = fmaf(acc[t][e], mv[t], xv[t][e]);
                ob[chn*HW_ + pp] = xn;
                if (chn == 3) xn3 = xn;
            }
            if (g == 0) ab[pp] = (xn3 > 0.1f) ? (unsigned char)1
                                              : (unsigned char)0;
        }
        __builtin_amdgcn_wave_barrier();   // h-tile reuse next strip
    }
}

// ---------------- k3: kill pixels with no alive neighbor ---------------------
__global__ __launch_bounds__(256) void nca_alive(
    const unsigned char* __restrict__ alpha, float* __restrict__ out)
{
    int t = blockIdx.x * blockDim.x + threadIdx.x;
    if (t >= B_*HW_) return;
    int b = t >> 16;
    int p = t & (HW_-1);
    int i = p >> 8;
    int j = p & (W_-1);
    const unsigned char* ab = alpha + (size_t)b * HW_;

    bool im = i > 0, ip = i < H_-1, jm = j > 0, jp = j < W_-1;
    int acc = ab[p];
    acc += jm ? ab[p-1] : 0;
    acc += jp ? ab[p+1] : 0;
    if (im) {
        acc += ab[p-W_];
        acc += jm ? ab[p-W_-1] : 0;
        acc += jp ? ab[p-W_+1] : 0;
    }
    if (ip) {
        acc += ab[p+W_];
        acc += jm ? ab[p+W_-1] : 0;
        acc += jp ? ab[p+W_+1] : 0;
    }
    if (acc == 0) {
        size_t base = (size_t)b * C_ * HW_ + p;
        #pragma unroll
        for (int c = 0; c < C_; ++c) out[base + (size_t)c * HW_] = 0.f;
    }
}

extern "C" void kernel_launch(void* const* d_in, const int* in_sizes, int n_in,
                              void* d_out, int out_size, void* d_ws, size_t ws_size,
                              hipStream_t stream)
{
    const float* x    = (const float*)d_in[0];
    const int*   mask = (const int*)d_in[1];
    const float* w1   = (const float*)d_in[2];
    const float* b1   = (const float*)d_in[3];
    const float* w2   = (const float*)d_in[4];
    const float* b2   = (const float*)d_in[5];
    float* out = (float*)d_out;

    // ws layout: xs (B*HW floats) | alpha (B*HW bytes) | coefH 1KB | w2h 4KB
    char* ws = (char*)d_ws;
    float*         xsbuf = (float*)ws;
    unsigned char* alpha = (unsigned char*)(ws + (size_t)B_*HW_*4);
    int4*          coefH = (int4*)(ws + (size_t)B_*HW_*5);
    short*         w2h   = (short*)(ws + (size_t)B_*HW_*5 + 1024);

    nca_prep<<<1, 128, 0, stream>>>(w1, b1, w2, coefH, w2h);

    int n4 = B_*HW_/4;
    nca_sum<<<(n4 + 255)/256, 256, 0, stream>>>(x, xsbuf);

    nca_mlp<<<B_*H_/4, 256, 0, stream>>>(x, mask, xsbuf, coefH, w2h, b2,
                                         out, alpha);

    int n = B_*HW_;
    nca_alive<<<(n + 255)/256, 256, 0, stream>>>(alpha, out);
}